// Round 10
// baseline (2903.371 us; speedup 1.0000x reference)
//
#include <hip/hip_runtime.h>

#define NT 512
#define ND 256
#define NH 1024
#define NB 64
// R10: R7 two-phase handoff (cheap flag detect + bf16 payload) with RT hiding:
//  - x_{t+1} prefetched to regs (HBM RT off critical path)
//  - flag load issued before x-MFMA (flag RT hidden under compute)
//  - per-producer-WAVE monotonic flags (no producer barrier, no drain-all)
//  - parity-double-buffered cpart (from R9): ONE __syncthreads per step
// All in-loop VMEM is volatile asm; vmcnt counts are deterministic:
//  step top outstanding = [flagstore, nt x4]; vmcnt(0) at flag check drains;
//  after data8+xpref4 issue, vmcnt(4) => data8 retired (oldest-first, m135).
// Grid 256 wgs = 4 bgs(16 batches) x 64 slices(16 rows); 4 waves; K split by wave.

typedef float f32x4 __attribute__((ext_vector_type(4)));
typedef short bf16x8 __attribute__((ext_vector_type(8)));

__device__ __forceinline__ unsigned short f2bf(float f) {     // RNE
  unsigned u = __builtin_bit_cast(unsigned, f);
  u += 0x7fffu + ((u >> 16) & 1u);
  return (unsigned short)(u >> 16);
}
__device__ __forceinline__ float bflo(unsigned u) {
  return __builtin_bit_cast(float, u << 16);
}
__device__ __forceinline__ float bfhi(unsigned u) {
  return __builtin_bit_cast(float, u & 0xffff0000u);
}
__device__ __forceinline__ bf16x8 pack8(float4 a, float4 b) {
  bf16x8 r;
  r[0] = (short)f2bf(a.x); r[1] = (short)f2bf(a.y);
  r[2] = (short)f2bf(a.z); r[3] = (short)f2bf(a.w);
  r[4] = (short)f2bf(b.x); r[5] = (short)f2bf(b.y);
  r[6] = (short)f2bf(b.z); r[7] = (short)f2bf(b.w);
  return r;
}

__global__ void __launch_bounds__(256, 1)
rnn_step_kernel(const float* __restrict__ x,
                const float* __restrict__ Wx_w,
                const float* __restrict__ Wx_b,
                const float* __restrict__ Wh_w,
                const float* __restrict__ Ws_w,
                const float* __restrict__ Ws_b,
                const float* __restrict__ Us_w,
                float* __restrict__ out,
                unsigned short* __restrict__ hbuf,   // bf16 [2][NB][NH]
                unsigned* __restrict__ flags)        // u32 [4][64][4] monotonic
{
  const int tid = (int)threadIdx.x;
  const int w   = tid >> 6;        // wave
  const int l   = tid & 63;        // lane
  const int bm  = l & 15;          // mfma row/col index for A/B frags
  const int lg  = l >> 4;          // lane group
  const int sl  = (int)blockIdx.x & 63;
  const int bg  = (int)blockIdx.x >> 6;
  const int r_base = sl * 16;
  const int b_base = bg * 16;
  const int ro = tid & 15;         // epilogue: consecutive lanes -> consecutive rows
  const int bo = tid >> 4;
  const int rg = r_base + ro;
  const int b_glob = b_base + bo;

  __shared__ unsigned short us_sh[1024];      // bf16 Us
  __shared__ float cpart[2][4][4][72];        // parity-buffered C partials
  __shared__ float gpart[2][4][16];           // parity-buffered gate partials

  // ---- one-time: Us -> bf16 LDS ----
  {
    const float4 uv = *(const float4*)(Us_w + tid*4);
    us_sh[tid*4+0] = f2bf(uv.x); us_sh[tid*4+1] = f2bf(uv.y);
    us_sh[tid*4+2] = f2bf(uv.z); us_sh[tid*4+3] = f2bf(uv.w);
  }

  // ---- A-fragments in registers (bf16), held all 512 steps ----
  // A layout (m89): row = l&15, k = ktile + (l>>4)*8 + j
  bf16x8 whf[8];   // wave w: h-K slice [w*256, +256) -> 8 mfma
  bf16x8 wxf[2];   // wave w: x-K slice [w*64, +64)   -> 2 mfma
  float4 wsf[4];   // Ws f32 slice for gate-x
  {
    const int ar = r_base + bm;
    #pragma unroll
    for (int m = 0; m < 8; ++m) {
      const int k0 = w*256 + m*32 + lg*8;
      const float4 f0 = *(const float4*)(Wh_w + (size_t)ar*NH + k0);
      const float4 f1 = *(const float4*)(Wh_w + (size_t)ar*NH + k0 + 4);
      whf[m] = pack8(f0, f1);
    }
    #pragma unroll
    for (int m = 0; m < 2; ++m) {
      const int k0 = w*64 + m*32 + lg*8;
      const float4 f0 = *(const float4*)(Wx_w + (size_t)ar*ND + k0);
      const float4 f1 = *(const float4*)(Wx_w + (size_t)ar*ND + k0 + 4);
      wxf[m] = pack8(f0, f1);
      wsf[m*2]   = *(const float4*)(Ws_w + k0);
      wsf[m*2+1] = *(const float4*)(Ws_w + k0 + 4);
    }
  }
  const float wxb_r = Wx_b[rg];
  const float whd_r = Wh_w[(size_t)rg*NH + rg];
  const float usr_r = Us_w[rg];
  const float wsb   = Ws_b[0];
  // force all loop-invariant loads to retire BEFORE the loop (no in-loop
  // compiler waitcnt on our asm-counted path)
  {
    float dummy = wxb_r + whd_r + usr_r + wsb;
    #pragma unroll
    for (int m = 0; m < 4; ++m)
      dummy += wsf[m].x + wsf[m].y + wsf[m].z + wsf[m].w;
    asm volatile("" :: "v"(dummy));
  }

  float* const hs_o = out + (size_t)NB*NT;
  float* const g_o  = hs_o + (size_t)NB*NT*NH;
  float* const l_o  = g_o  + (size_t)NB*NT*NH;
  float* const rd_o = l_o  + (size_t)NB*NT*NH;

  // consumer flag addresses: lane l polls (slice w*16 + l>>2, producer-wave l&3)
  const unsigned* fpoll = flags + ((size_t)(bg*64 + w*16 + (l >> 2))*4 + (l & 3));
  // producer flag address: this wg's slice, this wave
  unsigned* fstore = flags + ((size_t)(bg*64 + sl)*4 + w);

  __syncthreads();

  // ---- prologue: x_0 into registers (asm, then drain) ----
  float4 xq0, xq1, xq2, xq3;
  {
    const float* xr = x + ((size_t)(b_base + bm)*NT + 0)*ND + w*64 + lg*8;
    asm volatile(
      "global_load_dwordx4 %0, %4, off\n\t"
      "global_load_dwordx4 %1, %4, off offset:16\n\t"
      "global_load_dwordx4 %2, %4, off offset:128\n\t"
      "global_load_dwordx4 %3, %4, off offset:144\n\t"
      "s_waitcnt vmcnt(0)"
      : "=&v"(xq0), "=&v"(xq1), "=&v"(xq2), "=&v"(xq3)
      : "v"(xr) : "memory");
  }

  float myh = 0.f;

  for (int t = 0; t < NT; ++t) {
    const int p = t & 1;
    // ---- 1. early flag issue (RT hides under x-MFMA) ----
    unsigned flagv = 0;
    if (t > 0)
      asm volatile("global_load_dword %0, %1, off sc0 sc1"
                   : "=v"(flagv) : "v"(fpoll) : "memory");

    // ---- 2. x-part from prefetched regs: 2 mfma + gate-x (f32) ----
    f32x4 acc = {0.f, 0.f, 0.f, 0.f};
    float ga = wsf[0].x*xq0.x + wsf[0].y*xq0.y + wsf[0].z*xq0.z + wsf[0].w*xq0.w
             + wsf[1].x*xq1.x + wsf[1].y*xq1.y + wsf[1].z*xq1.z + wsf[1].w*xq1.w
             + wsf[2].x*xq2.x + wsf[2].y*xq2.y + wsf[2].z*xq2.z + wsf[2].w*xq2.w
             + wsf[3].x*xq3.x + wsf[3].y*xq3.y + wsf[3].z*xq3.z + wsf[3].w*xq3.w;
    acc = __builtin_amdgcn_mfma_f32_16x16x32_bf16(wxf[0], pack8(xq0, xq1), acc, 0, 0, 0);
    acc = __builtin_amdgcn_mfma_f32_16x16x32_bf16(wxf[1], pack8(xq2, xq3), acc, 0, 0, 0);

    uint4 hv0, hv1, hv2, hv3, hv4, hv5, hv6, hv7;
    const int tn = (t + 1 < NT) ? (t + 1) : t;   // xpref target
    const float* xrn = x + ((size_t)(b_base + bm)*NT + tn)*ND + w*64 + lg*8;

    if (t > 0) {
      // ---- 3. flag confirm (monotonic >= t); retries rare & cheap ----
      asm volatile("s_waitcnt vmcnt(0)" ::: "memory");
      while (!__all((int)(flagv >= (unsigned)t))) {
        __builtin_amdgcn_s_sleep(1);
        asm volatile("global_load_dword %0, %1, off sc0 sc1\n\t"
                     "s_waitcnt vmcnt(0)"
                     : "=v"(flagv) : "v"(fpoll) : "memory");
      }
      __builtin_amdgcn_sched_barrier(0);
      // ---- 4. data loads (bf16 B-frags, 8 x dwordx4) ----
      const unsigned short* hrow =
          hbuf + ((size_t)((t-1)&1)*NB + b_base + bm)*NH + w*256 + lg*8;
      asm volatile(
        "global_load_dwordx4 %0, %8, off sc0 sc1\n\t"
        "global_load_dwordx4 %1, %8, off offset:64 sc0 sc1\n\t"
        "global_load_dwordx4 %2, %8, off offset:128 sc0 sc1\n\t"
        "global_load_dwordx4 %3, %8, off offset:192 sc0 sc1\n\t"
        "global_load_dwordx4 %4, %8, off offset:256 sc0 sc1\n\t"
        "global_load_dwordx4 %5, %8, off offset:320 sc0 sc1\n\t"
        "global_load_dwordx4 %6, %8, off offset:384 sc0 sc1\n\t"
        "global_load_dwordx4 %7, %8, off offset:448 sc0 sc1"
        : "=&v"(hv0), "=&v"(hv1), "=&v"(hv2), "=&v"(hv3),
          "=&v"(hv4), "=&v"(hv5), "=&v"(hv6), "=&v"(hv7)
        : "v"(hrow) : "memory");
      // ---- 5. x prefetch for t+1 (drains at step-tail vmcnt(0), RT hidden) ----
      asm volatile(
        "global_load_dwordx4 %0, %4, off\n\t"
        "global_load_dwordx4 %1, %4, off offset:16\n\t"
        "global_load_dwordx4 %2, %4, off offset:128\n\t"
        "global_load_dwordx4 %3, %4, off offset:144"
        : "=&v"(xq0), "=&v"(xq1), "=&v"(xq2), "=&v"(xq3)
        : "v"(xrn) : "memory");
      // ---- 6. wait data8 only (oldest 8 of 12; xpref keeps flying) ----
      asm volatile("s_waitcnt vmcnt(4)" ::: "memory");
      __builtin_amdgcn_sched_barrier(0);
      // ---- 7. h-part: 8 mfma + gate-h ----
      const uint4 hva[8] = {hv0, hv1, hv2, hv3, hv4, hv5, hv6, hv7};
      #pragma unroll
      for (int m = 0; m < 8; ++m) {
        acc = __builtin_amdgcn_mfma_f32_16x16x32_bf16(
                whf[m], __builtin_bit_cast(bf16x8, hva[m]), acc, 0, 0, 0);
        const uint4 uu = *(const uint4*)&us_sh[w*256 + m*32 + lg*8];
        ga += bflo(uu.x)*bflo(hva[m].x) + bfhi(uu.x)*bfhi(hva[m].x)
            + bflo(uu.y)*bflo(hva[m].y) + bfhi(uu.y)*bfhi(hva[m].y)
            + bflo(uu.z)*bflo(hva[m].z) + bfhi(uu.z)*bfhi(hva[m].z)
            + bflo(uu.w)*bflo(hva[m].w) + bfhi(uu.w)*bfhi(hva[m].w);
      }
    } else {
      // t == 0: keep the xpref pattern identical
      asm volatile(
        "global_load_dwordx4 %0, %4, off\n\t"
        "global_load_dwordx4 %1, %4, off offset:16\n\t"
        "global_load_dwordx4 %2, %4, off offset:128\n\t"
        "global_load_dwordx4 %3, %4, off offset:144"
        : "=&v"(xq0), "=&v"(xq1), "=&v"(xq2), "=&v"(xq3)
        : "v"(xrn) : "memory");
    }

    // ---- 8. combine partials (parity LDS, single barrier) ----
    ga += __shfl_xor(ga, 16, 64);
    ga += __shfl_xor(ga, 32, 64);
    if (l < 16) gpart[p][w][l] = ga;
    cpart[p][w][0][l] = acc[0];
    cpart[p][w][1][l] = acc[1];
    cpart[p][w][2][l] = acc[2];
    cpart[p][w][3][l] = acc[3];
    __syncthreads();

    // ---- 9. epilogue: 1 output per thread (row ro, batch bo) ----
    // C mapping (m89): col(lane&15)=batch, row=(lane>>4)*4+reg
    const float gsum = gpart[p][0][bo] + gpart[p][1][bo] +
                       gpart[p][2][bo] + gpart[p][3][bo];
    const int ci = ro & 3, cl = ((ro >> 2) << 4) + bo;
    const float pre0 = cpart[p][0][ci][cl] + cpart[p][1][ci][cl] +
                       cpart[p][2][ci][cl] + cpart[p][3][ci][cl];
    const float sg   = 1.f / (1.f + expf(-(gsum + wsb)));
    const float pre  = pre0 + wxb_r;
    const float htld = tanhf(pre);
    const float hp   = myh;
    const float h    = (1.f - sg)*hp + sg*htld;
    myh = h;
    // ---- 10. h store (bf16, LLC) ----
    {
      const unsigned hb = (unsigned)f2bf(h);
      unsigned short* hptr = hbuf + ((size_t)p*NB + b_glob)*NH + rg;
      asm volatile("global_store_short %0, %1, off sc0 sc1"
                   :: "v"(hptr), "v"(hb) : "memory");
    }
    // ---- 11. drain own wave's stores (+xpref, long done) ----
    asm volatile("s_waitcnt vmcnt(0)" ::: "memory");
    // ---- 12. per-wave monotonic flag (no wg barrier) ----
    if (l == 0) {
      const unsigned word = (unsigned)(t + 1);
      asm volatile("global_store_dword %0, %1, off sc0 sc1"
                   :: "v"(fstore), "v"(word) : "memory");
    }
    // ---- 13. outputs (fire-and-forget; counted in next step's baseline) ----
    {
      const size_t obase = ((size_t)b_glob*NT + t)*NH + rg;
      const float sp = sg * (1.f - sg);
      __builtin_nontemporal_store(h, &hs_o[obase]);
      __builtin_nontemporal_store(sg, &g_o[obase]);
      __builtin_nontemporal_store(1.f - sg, &l_o[obase]);
      __builtin_nontemporal_store((htld - hp)*(sp*usr_r) + sg*(1.f - htld*htld)*whd_r,
                                  &rd_o[obase]);
    }
  }
}

// ys[b,t] = out_w . hs[b,t,:] + out_b
__global__ void yfinish_kernel(const float* __restrict__ hs,
                               const float* __restrict__ out_w,
                               const float* __restrict__ out_b,
                               float* __restrict__ ys)
{
  const int row  = (int)blockIdx.x*4 + ((int)threadIdx.x >> 6);
  const int lane = (int)threadIdx.x & 63;
  const float4* hp = (const float4*)(hs + (size_t)row*NH);
  const float4* wp = (const float4*)out_w;
  float s = 0.f;
  #pragma unroll
  for (int i = 0; i < 4; ++i) {
    const float4 h4 = hp[i*64 + lane];
    const float4 w4 = wp[i*64 + lane];
    s += h4.x*w4.x + h4.y*w4.y + h4.z*w4.z + h4.w*w4.w;
  }
  #pragma unroll
  for (int off = 32; off > 0; off >>= 1) s += __shfl_xor(s, off, 64);
  if (lane == 0) ys[row] = s + out_b[0];
}

extern "C" void kernel_launch(void* const* d_in, const int* in_sizes, int n_in,
                              void* d_out, int out_size, void* d_ws, size_t ws_size,
                              hipStream_t stream)
{
  (void)in_sizes; (void)n_in; (void)out_size; (void)ws_size;
  const float* x     = (const float*)d_in[0];
  const float* Wx_w  = (const float*)d_in[1];
  const float* Wx_b  = (const float*)d_in[2];
  const float* Wh_w  = (const float*)d_in[3];
  const float* Ws_w  = (const float*)d_in[4];
  const float* Ws_b  = (const float*)d_in[5];
  const float* Us_w  = (const float*)d_in[6];
  const float* out_w = (const float*)d_in[7];
  const float* out_b = (const float*)d_in[8];
  float* out = (float*)d_out;

  char* ws = (char*)d_ws;
  unsigned short* hbuf = (unsigned short*)ws;            // bf16, 256 KB
  unsigned* flags = (unsigned*)(ws + 262144);            // 4x64x4 u32 = 4 KB

  // reset monotonic flags each launch (cross-replay safety), 4 KB only
  hipMemsetAsync(flags, 0, (size_t)4*64*4*sizeof(unsigned), stream);
  rnn_step_kernel<<<dim3(256), dim3(256), 0, stream>>>(
      x, Wx_w, Wx_b, Wh_w, Ws_w, Ws_b, Us_w, out, hbuf, flags);
  yfinish_kernel<<<dim3((NB*NT)/4), dim3(256), 0, stream>>>(
      out + (size_t)NB*NT, out_w, out_b, out);
}

// Round 11
// 1818.774 us; speedup vs baseline: 1.5963x; 1.5963x over previous
//
#include <hip/hip_runtime.h>

#define NT 512
#define ND 256
#define NH 1024
#define NB 64
// R11 = R7 (best known: two-phase handoff, staging-free MFMA, 2 barriers/step)
// + ONE change: output stores DEFERRED by one step.
//   R7's poll vmcnt(0) waited on the previous step's 4 nontemporal HBM store
//   acks (vmcnt retires in issue order) — ~1us of HBM write-ack latency on the
//   serial critical path每step. Now step t's outputs are kept in 4 persistent
//   VGPRs and stored at step t+1 AFTER the 8 data loads: order [data8, outs4],
//   counted wait vmcnt(4) retires data only; outs drain at the tail vmcnt(0)
//   ~0.7us later (hidden under mfma+barrier+epilogue).
// Grid 256 wgs = 4 bgs(16 batches) x 64 slices(16 rows); 4 waves; K by wave.

typedef float f32x4 __attribute__((ext_vector_type(4)));
typedef short bf16x8 __attribute__((ext_vector_type(8)));

__device__ __forceinline__ unsigned short f2bf(float f) {     // RNE
  unsigned u = __builtin_bit_cast(unsigned, f);
  u += 0x7fffu + ((u >> 16) & 1u);
  return (unsigned short)(u >> 16);
}
__device__ __forceinline__ float bflo(unsigned u) {
  return __builtin_bit_cast(float, u << 16);
}
__device__ __forceinline__ float bfhi(unsigned u) {
  return __builtin_bit_cast(float, u & 0xffff0000u);
}
__device__ __forceinline__ bf16x8 pack8(float4 a, float4 b) {
  bf16x8 r;
  r[0] = (short)f2bf(a.x); r[1] = (short)f2bf(a.y);
  r[2] = (short)f2bf(a.z); r[3] = (short)f2bf(a.w);
  r[4] = (short)f2bf(b.x); r[5] = (short)f2bf(b.y);
  r[6] = (short)f2bf(b.z); r[7] = (short)f2bf(b.w);
  return r;
}

__global__ void __launch_bounds__(256, 1)
rnn_step_kernel(const float* __restrict__ x,
                const float* __restrict__ Wx_w,
                const float* __restrict__ Wx_b,
                const float* __restrict__ Wh_w,
                const float* __restrict__ Ws_w,
                const float* __restrict__ Ws_b,
                const float* __restrict__ Us_w,
                float* __restrict__ out,
                unsigned short* __restrict__ hbuf,   // bf16 [2][NB][NH]
                unsigned int* __restrict__ flags)    // [4][NT][64]
{
  const int tid = (int)threadIdx.x;
  const int w   = tid >> 6;        // wave
  const int l   = tid & 63;        // lane
  const int bm  = l & 15;          // mfma row/col index for A/B frags
  const int lg  = l >> 4;          // lane group
  const int sl  = (int)blockIdx.x & 63;
  const int bg  = (int)blockIdx.x >> 6;
  const int r_base = sl * 16;
  const int b_base = bg * 16;
  const int ro = tid & 15;         // epilogue: consecutive lanes -> consecutive rows
  const int bo = tid >> 4;
  const int rg = r_base + ro;
  const int b_glob = b_base + bo;

  __shared__ unsigned short us_sh[1024];   // bf16 Us (broadcast reads)
  __shared__ float cpart[4][4][72];        // per-wave C partials, padded
  __shared__ float gpart[4][16];           // per-wave gate partials

  // ---- one-time: Us -> bf16 LDS ----
  {
    const float4 uv = *(const float4*)(Us_w + tid*4);
    us_sh[tid*4+0] = f2bf(uv.x); us_sh[tid*4+1] = f2bf(uv.y);
    us_sh[tid*4+2] = f2bf(uv.z); us_sh[tid*4+3] = f2bf(uv.w);
  }

  // ---- A-fragments in registers (bf16), held all 512 steps ----
  // A layout (m89): row = l&15, k = ktile + (l>>4)*8 + j
  bf16x8 whf[8];   // wave w: h-K slice [w*256, w*256+256) -> 8 mfma
  bf16x8 wxf[2];   // wave w: x-K slice [w*64, w*64+64)    -> 2 mfma
  float4 wsf[4];   // Ws f32 slice for gate-x (exact f32 math)
  {
    const int ar = r_base + bm;
    #pragma unroll
    for (int m = 0; m < 8; ++m) {
      const int k0 = w*256 + m*32 + lg*8;
      const float4 f0 = *(const float4*)(Wh_w + (size_t)ar*NH + k0);
      const float4 f1 = *(const float4*)(Wh_w + (size_t)ar*NH + k0 + 4);
      whf[m] = pack8(f0, f1);
    }
    #pragma unroll
    for (int m = 0; m < 2; ++m) {
      const int k0 = w*64 + m*32 + lg*8;
      const float4 f0 = *(const float4*)(Wx_w + (size_t)ar*ND + k0);
      const float4 f1 = *(const float4*)(Wx_w + (size_t)ar*ND + k0 + 4);
      wxf[m] = pack8(f0, f1);
      wsf[m*2]   = *(const float4*)(Ws_w + k0);
      wsf[m*2+1] = *(const float4*)(Ws_w + k0 + 4);
    }
  }
  const float wxb_r = Wx_b[rg];
  const float whd_r = Wh_w[(size_t)rg*NH + rg];
  const float usr_r = Us_w[rg];
  const float wsb   = Ws_b[0];

  float* const hs_o = out + (size_t)NB*NT;
  float* const g_o  = hs_o + (size_t)NB*NT*NH;
  float* const l_o  = g_o  + (size_t)NB*NT*NH;
  float* const rd_o = l_o  + (size_t)NB*NT*NH;

  __syncthreads();

  float myh = 0.f;           // h_{t-1} for this (row,batch) — also deferred h out
  float p_sg = 0.f, p_htld = 0.f, p_hp = 0.f;   // step t-1 epilogue values

  for (int t = 0; t < NT; ++t) {
    // ---- x-part: direct f32 loads, in-reg pack, 2 mfma + gate-x (f32) ----
    f32x4 acc = {0.f, 0.f, 0.f, 0.f};
    float ga = 0.f;
    {
      const float* xrow = x + ((size_t)(b_base+bm)*NT + t)*ND + w*64 + lg*8;
      #pragma unroll
      for (int m = 0; m < 2; ++m) {
        const float4 f0 = *(const float4*)(xrow + m*32);
        const float4 f1 = *(const float4*)(xrow + m*32 + 4);
        acc = __builtin_amdgcn_mfma_f32_16x16x32_bf16(
                wxf[m], pack8(f0, f1), acc, 0, 0, 0);
        ga += wsf[m*2].x*f0.x + wsf[m*2].y*f0.y + wsf[m*2].z*f0.z + wsf[m*2].w*f0.w
            + wsf[m*2+1].x*f1.x + wsf[m*2+1].y*f1.y + wsf[m*2+1].z*f1.z + wsf[m*2+1].w*f1.w;
      }
    }

    // ---- wait for h_{t-1} (all waves poll; poll path now free of HBM acks) ----
    if (t > 0) {
      {
        const unsigned int* fp = flags + ((size_t)bg*NT + (t-1))*64 + l;
        while (true) {
          unsigned int v;
          asm volatile("global_load_dword %0, %1, off sc0 sc1\n\t"
                       "s_waitcnt vmcnt(0)"
                       : "=v"(v) : "v"(fp) : "memory");
          if (__all((int)(v != 0u))) break;
          __builtin_amdgcn_s_sleep(1);
        }
      }
      __builtin_amdgcn_sched_barrier(0);   // pin x-loads out of counted window
      // ---- data loads: 8 x dwordx4 (bf16 B-frags) ----
      const unsigned short* hrow =
          hbuf + ((size_t)((t-1)&1)*NB + b_base + bm)*NH + w*256 + lg*8;
      uint4 hv[8];
      #pragma unroll
      for (int m = 0; m < 8; ++m)
        asm volatile("global_load_dwordx4 %0, %1, off sc0 sc1"
                     : "=v"(hv[m]) : "v"(hrow + m*32) : "memory");
      // ---- DEFERRED outputs of step t-1 (issued after data8; drain at tail) ----
      {
        const size_t obase = ((size_t)b_glob*NT + (t-1))*NH + rg;
        const float sp  = p_sg * (1.f - p_sg);
        const float rdv = (p_htld - p_hp)*(sp*usr_r) +
                          p_sg*(1.f - p_htld*p_htld)*whd_r;
        const float lv  = 1.f - p_sg;
        asm volatile("global_store_dword %0, %1, off nt"
                     :: "v"(hs_o + obase), "v"(myh) : "memory");
        asm volatile("global_store_dword %0, %1, off nt"
                     :: "v"(g_o + obase), "v"(p_sg) : "memory");
        asm volatile("global_store_dword %0, %1, off nt"
                     :: "v"(l_o + obase), "v"(lv) : "memory");
        asm volatile("global_store_dword %0, %1, off nt"
                     :: "v"(rd_o + obase), "v"(rdv) : "memory");
      }
      // ---- counted wait: data8 retired, outs4 still in flight ----
      asm volatile("s_waitcnt vmcnt(4)" ::: "memory");
      __builtin_amdgcn_sched_barrier(0);
      // ---- h-part: 8 mfma + gate-h ----
      #pragma unroll
      for (int m = 0; m < 8; ++m) {
        acc = __builtin_amdgcn_mfma_f32_16x16x32_bf16(
                whf[m], __builtin_bit_cast(bf16x8, hv[m]), acc, 0, 0, 0);
        const uint4 uu = *(const uint4*)&us_sh[w*256 + m*32 + lg*8];
        ga += bflo(uu.x)*bflo(hv[m].x) + bfhi(uu.x)*bfhi(hv[m].x)
            + bflo(uu.y)*bflo(hv[m].y) + bfhi(uu.y)*bfhi(hv[m].y)
            + bflo(uu.z)*bflo(hv[m].z) + bfhi(uu.z)*bfhi(hv[m].z)
            + bflo(uu.w)*bflo(hv[m].w) + bfhi(uu.w)*bfhi(hv[m].w);
      }
    }

    // ---- combine partials ----
    ga += __shfl_xor(ga, 16, 64);
    ga += __shfl_xor(ga, 32, 64);
    if (l < 16) gpart[w][l] = ga;
    cpart[w][0][l] = acc[0];
    cpart[w][1][l] = acc[1];
    cpart[w][2][l] = acc[2];
    cpart[w][3][l] = acc[3];
    __syncthreads();                   // barrier (a)

    // ---- epilogue: 1 output per thread (row ro, batch bo) ----
    // C mapping (m89): col(lane&15)=batch, row=(lane>>4)*4+reg
    const float gsum = gpart[0][bo] + gpart[1][bo] + gpart[2][bo] + gpart[3][bo];
    const int ci = ro & 3, cl = ((ro >> 2) << 4) + bo;
    const float pre0 = cpart[0][ci][cl] + cpart[1][ci][cl] +
                       cpart[2][ci][cl] + cpart[3][ci][cl];
    const float sg   = 1.f / (1.f + expf(-(gsum + wsb)));
    const float pre  = pre0 + wxb_r;
    const float htld = tanhf(pre);
    const float hp   = myh;
    const float h    = (1.f - sg)*hp + sg*htld;
    // save step-t values for deferred store at step t+1
    myh = h; p_sg = sg; p_htld = htld; p_hp = hp;
    {
      const unsigned hb = (unsigned)f2bf(h);
      unsigned short* hptr = hbuf + ((size_t)(t & 1)*NB + b_glob)*NH + rg;
      asm volatile("global_store_short %0, %1, off sc0 sc1"
                   :: "v"(hptr), "v"(hb) : "memory");
    }
    asm volatile("s_waitcnt vmcnt(0)" ::: "memory");
    __syncthreads();                   // barrier (b): all h stores at LLC
    if (tid == 0) {
      unsigned int one = 1u;
      unsigned int* fp = flags + ((size_t)bg*NT + t)*64 + sl;
      asm volatile("global_store_dword %0, %1, off sc0 sc1"
                   :: "v"(fp), "v"(one) : "memory");
    }
  }

  // ---- final step's deferred outputs ----
  {
    const size_t obase = ((size_t)b_glob*NT + (NT-1))*NH + rg;
    const float sp  = p_sg * (1.f - p_sg);
    const float rdv = (p_htld - p_hp)*(sp*usr_r) +
                      p_sg*(1.f - p_htld*p_htld)*whd_r;
    __builtin_nontemporal_store(myh, &hs_o[obase]);
    __builtin_nontemporal_store(p_sg, &g_o[obase]);
    __builtin_nontemporal_store(1.f - p_sg, &l_o[obase]);
    __builtin_nontemporal_store(rdv, &rd_o[obase]);
  }
}

// ys[b,t] = out_w . hs[b,t,:] + out_b
__global__ void yfinish_kernel(const float* __restrict__ hs,
                               const float* __restrict__ out_w,
                               const float* __restrict__ out_b,
                               float* __restrict__ ys)
{
  const int row  = (int)blockIdx.x*4 + ((int)threadIdx.x >> 6);
  const int lane = (int)threadIdx.x & 63;
  const float4* hp = (const float4*)(hs + (size_t)row*NH);
  const float4* wp = (const float4*)out_w;
  float s = 0.f;
  #pragma unroll
  for (int i = 0; i < 4; ++i) {
    const float4 h4 = hp[i*64 + lane];
    const float4 w4 = wp[i*64 + lane];
    s += h4.x*w4.x + h4.y*w4.y + h4.z*w4.z + h4.w*w4.w;
  }
  #pragma unroll
  for (int off = 32; off > 0; off >>= 1) s += __shfl_xor(s, off, 64);
  if (lane == 0) ys[row] = s + out_b[0];
}

extern "C" void kernel_launch(void* const* d_in, const int* in_sizes, int n_in,
                              void* d_out, int out_size, void* d_ws, size_t ws_size,
                              hipStream_t stream)
{
  (void)in_sizes; (void)n_in; (void)out_size; (void)ws_size;
  const float* x     = (const float*)d_in[0];
  const float* Wx_w  = (const float*)d_in[1];
  const float* Wx_b  = (const float*)d_in[2];
  const float* Wh_w  = (const float*)d_in[3];
  const float* Ws_w  = (const float*)d_in[4];
  const float* Ws_b  = (const float*)d_in[5];
  const float* Us_w  = (const float*)d_in[6];
  const float* out_w = (const float*)d_in[7];
  const float* out_b = (const float*)d_in[8];
  float* out = (float*)d_out;

  char* ws = (char*)d_ws;
  unsigned short* hbuf = (unsigned short*)ws;                 // bf16, 256 KB
  unsigned int* flags  = (unsigned int*)(ws + 262144);        // 512 KB

  hipMemsetAsync(flags, 0, (size_t)4*NT*64*sizeof(unsigned int), stream);
  rnn_step_kernel<<<dim3(256), dim3(256), 0, stream>>>(
      x, Wx_w, Wx_b, Wh_w, Ws_w, Ws_b, Us_w, out, hbuf, flags);
  yfinish_kernel<<<dim3((NB*NT)/4), dim3(256), 0, stream>>>(
      out + (size_t)NB*NT, out_w, out_b, out);
}